// Round 2
// baseline (247.687 us; speedup 1.0000x reference)
//
#include <hip/hip_runtime.h>

// Strategy: MLP output depends only on X[b] (S=1000 distinct values).
// Compute MLP over the 1000 embedding rows -> params table, gather by X in
// the scan. Scan is the only O(B*T) work: memory-bound.
//
// Dtype is detected AT RUNTIME on device (reference says f32, test label says
// bf16 — conflicting). detect_dtype inspects embed bit patterns; all float
// inputs are canonicalized to bf16 in ws; scan emits bf16 or f32 per flag.

typedef unsigned int uint;
typedef unsigned short ushort_t;
typedef __attribute__((ext_vector_type(8))) short short8;
typedef __attribute__((ext_vector_type(4))) float f32x4;

#define SS 1000
#define HH 512
#define TT 200
#define BB_ 65536
#define PP 5

// conv region element offsets (bf16 canonical copies of the float inputs)
#define OFF_EMB   0
#define OFF_W1    512000
#define OFF_B1    774144
#define OFF_W2    774656
#define OFF_B2    1036800
#define OFF_WOUT  1037312
#define OFF_BOUT  1039872
#define CONV_TOT  1039877

__device__ __forceinline__ float b2f(ushort_t u) {
    return __uint_as_float(((uint)u) << 16);
}
__device__ __forceinline__ ushort_t f2b(float f) {
    uint u = __float_as_uint(f);
    uint r = u + 0x7FFFu + ((u >> 16) & 1u);   // RNE
    return (ushort_t)(r >> 16);
}

// ------------------------------------------------------------- dtype detect
// If embed is bf16: low 16 bits of each dword are a bf16 of ~N(0,1) ->
// exponent in [117,130] with ~95% prob. If f32: those bits are mantissa
// (uniform) -> ~5%. Count over 64 dwords, threshold 32.
__global__ void detect_dtype(const uint* __restrict__ embed_raw,
                             int* __restrict__ flag) {
    int lane = threadIdx.x;
    uint w = embed_raw[lane];
    uint e = (w >> 7) & 0xFFu;          // exponent field of low-half bf16
    bool plaus = (e >= 117u && e <= 130u);
    unsigned long long m = __ballot(plaus);
    if (lane == 0) flag[0] = (__popcll(m) >= 32) ? 1 : 0;
}

// ------------------------------------------------------- canonicalize -> bf16
__global__ __launch_bounds__(256) void convert_inputs(
    const void* __restrict__ embed, const void* __restrict__ W1,
    const void* __restrict__ b1,    const void* __restrict__ W2,
    const void* __restrict__ b2,    const void* __restrict__ Wout,
    const void* __restrict__ bout,  const int* __restrict__ flag,
    ushort_t* __restrict__ dst)
{
    int i = blockIdx.x * 256 + threadIdx.x;
    if (i >= CONV_TOT) return;
    const void* src; int off;
    if      (i < OFF_W1)   { src = embed; off = i; }
    else if (i < OFF_B1)   { src = W1;    off = i - OFF_W1; }
    else if (i < OFF_W2)   { src = b1;    off = i - OFF_B1; }
    else if (i < OFF_B2)   { src = W2;    off = i - OFF_W2; }
    else if (i < OFF_WOUT) { src = b2;    off = i - OFF_B2; }
    else if (i < OFF_BOUT) { src = Wout;  off = i - OFF_WOUT; }
    else                   { src = bout;  off = i - OFF_BOUT; }
    ushort_t v;
    if (flag[0]) v = ((const ushort_t*)src)[off];
    else         v = f2b(((const float*)src)[off]);
    dst[i] = v;
}

// ---------------------------------------------------------------- transpose
__global__ __launch_bounds__(256) void transpose_w(
    const ushort_t* __restrict__ conv, ushort_t* __restrict__ WT1,
    ushort_t* __restrict__ WT2)
{
    __shared__ ushort_t t[32][33];
    const ushort_t* W = conv + (blockIdx.z ? OFF_W2 : OFF_W1);
    ushort_t* WT = blockIdx.z ? WT2 : WT1;
    int k0 = blockIdx.x * 32, n0 = blockIdx.y * 32;
    int tx = threadIdx.x, ty = threadIdx.y;       // block (32,8)
    for (int i = ty; i < 32; i += 8)
        t[i][tx] = W[(k0 + i) * HH + n0 + tx];
    __syncthreads();
    for (int i = ty; i < 32; i += 8)
        WT[(n0 + i) * HH + k0 + tx] = t[tx][i];
}

// ---------------------------------------------------------------- MLP layer
// H[m][n] = relu(sum_k A[m][k] W[k][n] + bias[n]); WT = W transposed.
// Wave computes 16x64 via 4 MFMA accumulators; fragments direct from global.
__global__ __launch_bounds__(256) void mlp_layer(
    const ushort_t* __restrict__ A, const ushort_t* __restrict__ WT,
    const ushort_t* __restrict__ bias, ushort_t* __restrict__ H, int Mclamp)
{
    int tid = threadIdx.x;
    int lane = tid & 63;
    int wave = tid >> 6;
    int m_base = blockIdx.x * 64 + wave * 16;
    int n_base = blockIdx.y * 64;
    int lrow = lane & 15;
    int q = lane >> 4;
    int rowA = m_base + lrow; if (rowA > Mclamp) rowA = Mclamp;

    const short8* Ap  = (const short8*)(A + (size_t)rowA * HH) + q;
    const short8* Bp0 = (const short8*)(WT + (size_t)(n_base + 0 * 16 + lrow) * HH) + q;
    const short8* Bp1 = (const short8*)(WT + (size_t)(n_base + 1 * 16 + lrow) * HH) + q;
    const short8* Bp2 = (const short8*)(WT + (size_t)(n_base + 2 * 16 + lrow) * HH) + q;
    const short8* Bp3 = (const short8*)(WT + (size_t)(n_base + 3 * 16 + lrow) * HH) + q;

    f32x4 acc0 = {0.f,0.f,0.f,0.f}, acc1 = {0.f,0.f,0.f,0.f};
    f32x4 acc2 = {0.f,0.f,0.f,0.f}, acc3 = {0.f,0.f,0.f,0.f};

    #pragma unroll 4
    for (int kk = 0; kk < 16; kk++) {
        short8 a  = Ap[kk * 4];
        short8 b0 = Bp0[kk * 4];
        short8 b1v = Bp1[kk * 4];
        short8 b2v = Bp2[kk * 4];
        short8 b3v = Bp3[kk * 4];
        acc0 = __builtin_amdgcn_mfma_f32_16x16x32_bf16(a, b0,  acc0, 0, 0, 0);
        acc1 = __builtin_amdgcn_mfma_f32_16x16x32_bf16(a, b1v, acc1, 0, 0, 0);
        acc2 = __builtin_amdgcn_mfma_f32_16x16x32_bf16(a, b2v, acc2, 0, 0, 0);
        acc3 = __builtin_amdgcn_mfma_f32_16x16x32_bf16(a, b3v, acc3, 0, 0, 0);
    }

    int orow = m_base + q * 4;
    f32x4 accs[4] = {acc0, acc1, acc2, acc3};
    #pragma unroll
    for (int nt = 0; nt < 4; nt++) {
        int n = n_base + nt * 16 + lrow;
        float bb = b2f(bias[n]);
        #pragma unroll
        for (int r = 0; r < 4; r++) {
            float v = accs[nt][r] + bb;
            H[(size_t)(orow + r) * HH + n] = f2b(fmaxf(v, 0.f));
        }
    }
}

// ---------------------------------------------------------------- params
__global__ __launch_bounds__(256) void params_kernel(
    const ushort_t* __restrict__ h2, const ushort_t* __restrict__ conv,
    float* __restrict__ table)
{
    int wid = blockIdx.x * 4 + (threadIdx.x >> 6);
    int lane = threadIdx.x & 63;
    if (wid >= SS * PP) return;
    int row = wid / PP, p = wid - row * PP;
    const ushort_t* Wout = conv + OFF_WOUT;
    const ushort_t* bout = conv + OFF_BOUT;
    const short8* hr = (const short8*)(h2 + (size_t)row * HH);
    short8 h = hr[lane];
    float acc = 0.f;
    #pragma unroll
    for (int j = 0; j < 8; j++) {
        int k = lane * 8 + j;
        acc += b2f((ushort_t)h[j]) * b2f(Wout[k * PP + p]);
    }
    #pragma unroll
    for (int m = 32; m; m >>= 1) acc += __shfl_xor(acc, m);
    if (lane == 0) {
        float x = acc + b2f(bout[p]);
        float sg = 1.f / (1.f + expf(-x));
        sg = fminf(fmaxf(sg, 1e-6f), 1.f - 1e-6f);
        table[(size_t)row * 8 + p] = sg;
    }
}

// ---------------------------------------------------------------- scan
__global__ __launch_bounds__(64) void scan_kernel(
    const int* __restrict__ X, const int* __restrict__ y,
    const float* __restrict__ table, const int* __restrict__ flag,
    void* __restrict__ out)
{
    __shared__ uint y_su[64 * 11];
    __shared__ uint cs[64 * 41];
    __shared__ uint lsb[64 * 41];
    int tid = threadIdx.x;
    int b0 = blockIdx.x * 64;
    int b = b0 + tid;
    int fb = flag[0];                           // grid-uniform
    int xi = X[b]; xi = xi < 0 ? 0 : (xi >= SS ? SS - 1 : xi);
    float l      = table[xi * 8 + 0];
    float p1     = table[xi * 8 + 1];
    float g      = table[xi * 8 + 2];
    float s      = table[xi * 8 + 3];
    float latent = table[xi * 8 + 4];

    if (fb) {
        ushort_t* pout = (ushort_t*)out + 2ull * BB_ * TT + (size_t)b * 5;
        pout[0] = f2b(l); pout[1] = f2b(p1); pout[2] = f2b(g);
        pout[3] = f2b(s); pout[4] = f2b(latent);
    } else {
        float* pout = (float*)out + 2ull * BB_ * TT + (size_t)b * 5;
        pout[0] = l; pout[1] = p1; pout[2] = g; pout[3] = s; pout[4] = latent;
    }

    char* cgb = (char*)out;
    char* lgb = (char*)out + (fb ? 2ull : 4ull) * BB_ * TT;
    float oms = 1.f - s, omg = 1.f - g;

    for (int chunk = 0; chunk < 5; chunk++) {
        int c0 = chunk * 40;
        __syncthreads();
        // stage y: 64 rows x 10 int4 groups, coalesced
        #pragma unroll
        for (int k2 = 0; k2 < 10; k2++) {
            int gix = tid + k2 * 64;
            int r = gix / 10, q2 = gix - r * 10;
            int4 v = *(const int4*)(y + (size_t)(b0 + r) * TT + c0 + q2 * 4);
            uint pk = (uint)(v.x == 1) | ((uint)(v.y == 1) << 8) |
                      ((uint)(v.z == 1) << 16) | ((uint)(v.w == 1) << 24);
            y_su[r * 11 + q2] = pk;
        }
        __syncthreads();
        // 40 scan steps
        #pragma unroll
        for (int j4 = 0; j4 < 10; j4++) {
            uint u = y_su[tid * 11 + j4];
            float cv[4], lv[4];
            #pragma unroll
            for (int i = 0; i < 4; i++) {
                float num1    = latent * oms;
                float correct = num1 + (1.f - latent) * g;
                float lat_s   = latent * s;
                bool yt = (u >> (8 * i)) & 1u;
                float num = yt ? num1 : lat_s;
                float den = yt ? correct : (lat_s + (1.f - latent) * omg);
                float kt = num / den;
                cv[i] = correct;
                lv[i] = latent;
                float nxt = kt + (1.f - kt) * l;
                latent = fminf(fmaxf(nxt, 1e-6f), 1.f - 1e-6f);
            }
            if (fb) {
                cs[tid * 41 + j4 * 2]      = (uint)f2b(cv[0]) | ((uint)f2b(cv[1]) << 16);
                cs[tid * 41 + j4 * 2 + 1]  = (uint)f2b(cv[2]) | ((uint)f2b(cv[3]) << 16);
                lsb[tid * 41 + j4 * 2]     = (uint)f2b(lv[0]) | ((uint)f2b(lv[1]) << 16);
                lsb[tid * 41 + j4 * 2 + 1] = (uint)f2b(lv[2]) | ((uint)f2b(lv[3]) << 16);
            } else {
                #pragma unroll
                for (int i = 0; i < 4; i++) {
                    cs[tid * 41 + j4 * 4 + i]  = __float_as_uint(cv[i]);
                    lsb[tid * 41 + j4 * 4 + i] = __float_as_uint(lv[i]);
                }
            }
        }
        __syncthreads();
        if (fb) {   // bf16: 20 uints (80B) per row per chunk
            #pragma unroll
            for (int k2 = 0; k2 < 20; k2++) {
                int gix = tid + k2 * 64;
                int r = gix / 20, q2 = gix - r * 20;
                size_t off = (size_t)(b0 + r) * 400 + (size_t)c0 * 2 + q2 * 4;
                *(uint*)(cgb + off) = cs[r * 41 + q2];
                *(uint*)(lgb + off) = lsb[r * 41 + q2];
            }
        } else {    // f32: 40 uints (160B) per row per chunk
            #pragma unroll
            for (int k2 = 0; k2 < 40; k2++) {
                int gix = tid + k2 * 64;
                int r = gix / 40, q2 = gix - r * 40;
                size_t off = (size_t)(b0 + r) * 800 + (size_t)c0 * 4 + q2 * 4;
                *(uint*)(cgb + off) = cs[r * 41 + q2];
                *(uint*)(lgb + off) = lsb[r * 41 + q2];
            }
        }
    }
}

// ---------------------------------------------------------------- launch
extern "C" void kernel_launch(void* const* d_in, const int* in_sizes, int n_in,
                              void* d_out, int out_size, void* d_ws, size_t ws_size,
                              hipStream_t stream) {
    const int* X = (const int*)d_in[0];
    const int* y = (const int*)d_in[1];

    char* ws = (char*)d_ws;
    ushort_t* conv  = (ushort_t*)(ws);                 // 2,079,754 B used
    ushort_t* WT1   = (ushort_t*)(ws + 2097152);       // 512 KB
    ushort_t* WT2   = (ushort_t*)(ws + 2621440);       // 512 KB
    ushort_t* h1    = (ushort_t*)(ws + 3145728);       // 1 MB (1024x512 bf16)
    ushort_t* h2    = (ushort_t*)(ws + 4194304);       // 1 MB
    float*    table = (float*)(ws + 5242880);          // 32 KB
    int*      flag  = (int*)(ws + 5275648);            // 4 B

    detect_dtype<<<1, 64, 0, stream>>>((const uint*)d_in[2], flag);
    convert_inputs<<<(CONV_TOT + 255) / 256, 256, 0, stream>>>(
        d_in[2], d_in[3], d_in[4], d_in[5], d_in[6], d_in[7], d_in[8],
        flag, conv);
    transpose_w<<<dim3(16, 16, 2), dim3(32, 8, 1), 0, stream>>>(conv, WT1, WT2);
    mlp_layer<<<dim3(16, 8, 1), 256, 0, stream>>>(conv + OFF_EMB, WT1, conv + OFF_B1, h1, SS - 1);
    mlp_layer<<<dim3(16, 8, 1), 256, 0, stream>>>(h1, WT2, conv + OFF_B2, h2, 1023);
    params_kernel<<<dim3(1250, 1, 1), 256, 0, stream>>>(h2, conv, table);
    scan_kernel<<<dim3(BB_ / 64, 1, 1), 64, 0, stream>>>(X, y, table, flag, (void*)d_out);
}

// Round 3
// 218.748 us; speedup vs baseline: 1.1323x; 1.1323x over previous
//
#include <hip/hip_runtime.h>

// MLP depends only on X[b] (1000 distinct values) -> compute params table
// once over embedding rows, gather in the scan. Scan = one thread per row
// (sequential in T), grid-capped at 1 wave/SIMD -> must be ILP-optimized:
// all y staged to LDS nibbles up-front, outputs staged in LDS per 40-step
// chunk, global stores fire-and-forget. Dtype (f32 vs bf16) detected per
// wave from embed bit patterns (R2 proved f32 on this dataset; keep both).

typedef unsigned int uint;
typedef unsigned char uchar;
typedef unsigned short ushort_t;
typedef __attribute__((ext_vector_type(8))) short short8;
typedef __attribute__((ext_vector_type(4))) float f32x4;

#define SS 1000
#define HH 512
#define TT 200
#define BB_ 65536
#define PP 5

// conv region element offsets (bf16 canonical copies; W1/W2 not needed here,
// only their transposes)
#define OFF_EMB   0
#define OFF_B1    512000
#define OFF_B2    512512
#define OFF_WOUT  513024
#define OFF_BOUT  515584
#define CONV_TOT  515589

__device__ __forceinline__ float b2f(ushort_t u) {
    return __uint_as_float(((uint)u) << 16);
}
__device__ __forceinline__ ushort_t f2b(float f) {
    uint u = __float_as_uint(f);
    uint r = u + 0x7FFFu + ((u >> 16) & 1u);   // RNE
    return (ushort_t)(r >> 16);
}
// Per-wave dtype detect: low 16 bits of embed dwords are a plausible-exponent
// bf16 (~95% of N(0,1) values) iff data is bf16; uniform mantissa bits (~5%)
// iff f32. Ballot over 64 lanes, threshold 32. Wave-uniform, deterministic.
__device__ __forceinline__ int detect_bf16(const uint* __restrict__ embed_raw,
                                           int tid) {
    uint w = embed_raw[tid & 63];
    uint e = (w >> 7) & 0xFFu;
    bool pl = (e >= 117u && e <= 130u);
    return __popcll(__ballot(pl)) >= 32 ? 1 : 0;
}
__device__ __forceinline__ ushort_t ld_bf16(const void* src, int idx, int fb) {
    return fb ? ((const ushort_t*)src)[idx] : f2b(((const float*)src)[idx]);
}

// ------------------------------------------------------------------- prep
// Sections by blockIdx: [0,2015) conv copy; [2015,2527) 32x32 transpose
// tiles of W1/W2 (read raw, emit bf16 WT).
__global__ __launch_bounds__(256) void prep_kernel(
    const void* __restrict__ embed, const void* __restrict__ W1,
    const void* __restrict__ b1,    const void* __restrict__ W2,
    const void* __restrict__ b2,    const void* __restrict__ Wout,
    const void* __restrict__ bout,
    ushort_t* __restrict__ conv, ushort_t* __restrict__ WT1,
    ushort_t* __restrict__ WT2)
{
    int tid = threadIdx.x;
    int fb = detect_bf16((const uint*)embed, tid);
    int bx = blockIdx.x;
    if (bx < 2015) {
        int i = bx * 256 + tid;
        if (i < CONV_TOT) {
            const void* src; int off;
            if      (i < OFF_B1)   { src = embed; off = i; }
            else if (i < OFF_B2)   { src = b1;    off = i - OFF_B1; }
            else if (i < OFF_WOUT) { src = b2;    off = i - OFF_B2; }
            else if (i < OFF_BOUT) { src = Wout;  off = i - OFF_WOUT; }
            else                   { src = bout;  off = i - OFF_BOUT; }
            conv[i] = ld_bf16(src, off, fb);
        }
    } else {
        __shared__ ushort_t t[32][33];
        int bi = bx - 2015;                    // 0..511
        const void* W = bi < 256 ? W1 : W2;
        ushort_t* WT = bi < 256 ? WT1 : WT2;
        int ti = bi & 255;
        int k0 = (ti & 15) * 32, n0 = (ti >> 4) * 32;
        int tx = tid & 31, ty = tid >> 5;      // 32 x 8
        #pragma unroll
        for (int i = ty; i < 32; i += 8)
            t[i][tx] = ld_bf16(W, (k0 + i) * HH + n0 + tx, fb);
        __syncthreads();
        #pragma unroll
        for (int i = ty; i < 32; i += 8)
            WT[(n0 + i) * HH + k0 + tx] = t[tx][i];
    }
}

// -------------------------------------------------------------- MLP layer
// H[m][n] = relu(sum_k A[m][k] W[k][n] + bias[n]); WT = W transposed.
// Wave computes 16x64 via 4 MFMA accs; fragments direct from global (L2).
__global__ __launch_bounds__(256) void mlp_layer(
    const ushort_t* __restrict__ A, const ushort_t* __restrict__ WT,
    const ushort_t* __restrict__ bias, ushort_t* __restrict__ H, int Mclamp)
{
    int tid = threadIdx.x;
    int lane = tid & 63;
    int wave = tid >> 6;
    int m_base = blockIdx.x * 64 + wave * 16;
    int n_base = blockIdx.y * 64;
    int lrow = lane & 15;
    int q = lane >> 4;
    int rowA = m_base + lrow; if (rowA > Mclamp) rowA = Mclamp;

    const short8* Ap  = (const short8*)(A + (size_t)rowA * HH) + q;
    const short8* Bp0 = (const short8*)(WT + (size_t)(n_base + 0 * 16 + lrow) * HH) + q;
    const short8* Bp1 = (const short8*)(WT + (size_t)(n_base + 1 * 16 + lrow) * HH) + q;
    const short8* Bp2 = (const short8*)(WT + (size_t)(n_base + 2 * 16 + lrow) * HH) + q;
    const short8* Bp3 = (const short8*)(WT + (size_t)(n_base + 3 * 16 + lrow) * HH) + q;

    f32x4 acc0 = {0.f,0.f,0.f,0.f}, acc1 = {0.f,0.f,0.f,0.f};
    f32x4 acc2 = {0.f,0.f,0.f,0.f}, acc3 = {0.f,0.f,0.f,0.f};

    #pragma unroll 4
    for (int kk = 0; kk < 16; kk++) {
        short8 a   = Ap[kk * 4];
        short8 b0  = Bp0[kk * 4];
        short8 b1v = Bp1[kk * 4];
        short8 b2v = Bp2[kk * 4];
        short8 b3v = Bp3[kk * 4];
        acc0 = __builtin_amdgcn_mfma_f32_16x16x32_bf16(a, b0,  acc0, 0, 0, 0);
        acc1 = __builtin_amdgcn_mfma_f32_16x16x32_bf16(a, b1v, acc1, 0, 0, 0);
        acc2 = __builtin_amdgcn_mfma_f32_16x16x32_bf16(a, b2v, acc2, 0, 0, 0);
        acc3 = __builtin_amdgcn_mfma_f32_16x16x32_bf16(a, b3v, acc3, 0, 0, 0);
    }

    int orow = m_base + q * 4;                 // C/D: col=lane&15, row=q*4+reg
    f32x4 accs[4] = {acc0, acc1, acc2, acc3};
    #pragma unroll
    for (int nt = 0; nt < 4; nt++) {
        int n = n_base + nt * 16 + lrow;
        float bb = b2f(bias[n]);
        #pragma unroll
        for (int r = 0; r < 4; r++) {
            float v = accs[nt][r] + bb;
            H[(size_t)(orow + r) * HH + n] = f2b(fmaxf(v, 0.f));
        }
    }
}

// ---------------------------------------------------------------- params
__global__ __launch_bounds__(256) void params_kernel(
    const ushort_t* __restrict__ h2, const ushort_t* __restrict__ conv,
    float* __restrict__ table)
{
    int wid = blockIdx.x * 4 + (threadIdx.x >> 6);
    int lane = threadIdx.x & 63;
    if (wid >= SS * PP) return;
    int row = wid / PP, p = wid - row * PP;
    const ushort_t* Wout = conv + OFF_WOUT;
    const ushort_t* bout = conv + OFF_BOUT;
    const short8* hr = (const short8*)(h2 + (size_t)row * HH);
    short8 h = hr[lane];
    float acc = 0.f;
    #pragma unroll
    for (int j = 0; j < 8; j++) {
        int k = lane * 8 + j;
        acc += b2f((ushort_t)h[j]) * b2f(Wout[k * PP + p]);
    }
    #pragma unroll
    for (int m = 32; m; m >>= 1) acc += __shfl_xor(acc, m);
    if (lane == 0) {
        float x = acc + b2f(bout[p]);
        float sg = 1.f / (1.f + expf(-x));
        sg = fminf(fmaxf(sg, 1e-6f), 1.f - 1e-6f);
        table[(size_t)row * 8 + p] = sg;
    }
}

// ------------------------------------------------------------------ scan
// One thread per row. y staged ONCE to LDS nibbles (no global loads in the
// 200-step loop). Outputs staged per 40-step chunk in LDS, cooperatively
// stored (uint2 f32 / uint bf16). Only vmcnt wait is the one-time y stage.
__global__ __launch_bounds__(64) void scan_kernel(
    const int* __restrict__ X, const int* __restrict__ y,
    const float* __restrict__ table, const uint* __restrict__ embed_raw,
    void* __restrict__ out)
{
    __shared__ uchar yb[64 * 52];                       // 4 bits per byte
    __shared__ __align__(16) uint stg[2][64 * 42];      // f32: stride 42; bf16: 21
    int tid = threadIdx.x;
    int b0 = blockIdx.x * 64;
    int b = b0 + tid;
    int fb = detect_bf16(embed_raw, tid);

    // ---- stage ALL y: 64 rows x 50 int4, coalesced; pack to 4-bit nibbles
    #pragma unroll
    for (int k2 = 0; k2 < 50; k2++) {
        int gix = tid + k2 * 64;
        int r = gix / 50, q = gix - r * 50;
        int4 v = *(const int4*)(y + (size_t)(b0 + r) * TT + q * 4);
        yb[r * 52 + q] = (uchar)((uint)(v.x == 1) | ((uint)(v.y == 1) << 1) |
                                 ((uint)(v.z == 1) << 2) | ((uint)(v.w == 1) << 3));
    }

    int xi = X[b]; xi = xi < 0 ? 0 : (xi >= SS ? SS - 1 : xi);
    float l      = table[xi * 8 + 0];
    float p1     = table[xi * 8 + 1];
    float g      = table[xi * 8 + 2];
    float s      = table[xi * 8 + 3];
    float latent = table[xi * 8 + 4];

    if (fb) {
        ushort_t* pout = (ushort_t*)out + 2ull * BB_ * TT + (size_t)b * 5;
        pout[0] = f2b(l); pout[1] = f2b(p1); pout[2] = f2b(g);
        pout[3] = f2b(s); pout[4] = f2b(latent);
    } else {
        float* pout = (float*)out + 2ull * BB_ * TT + (size_t)b * 5;
        pout[0] = l; pout[1] = p1; pout[2] = g; pout[3] = s; pout[4] = latent;
    }

    char* cgb = (char*)out;
    char* lgb = (char*)out + (fb ? 2ull : 4ull) * BB_ * TT;
    float oms = 1.f - s;
    float omg = 1.f - g;
    float A1  = 1.f - s - g;       // correct = L*A1 + g
    float A0  = s + g - 1.f;       // den0    = L*A0 + omg
    float oml = 1.f - l;           // next    = kt*oml + l

    __syncthreads();

    for (int c = 0; c < 5; c++) {
        // ---- 40 steps, outputs into LDS rows
        #pragma unroll
        for (int j4 = 0; j4 < 10; j4++) {
            uint u = yb[tid * 52 + c * 10 + j4];
            uint pc0 = 0, pc1 = 0, pl0 = 0, pl1 = 0;   // bf16 pack regs
            #pragma unroll
            for (int i = 0; i < 4; i++) {
                float num1    = latent * oms;
                float correct = fmaf(latent, A1, g);
                float lats    = latent * s;
                bool yt = (u >> i) & 1u;
                float num = yt ? num1 : lats;
                float den = yt ? correct : fmaf(latent, A0, omg);
                float kt  = num * __builtin_amdgcn_rcpf(den);
                if (!fb) {
                    stg[0][tid * 42 + j4 * 4 + i] = __float_as_uint(correct);
                    stg[1][tid * 42 + j4 * 4 + i] = __float_as_uint(latent);
                } else {
                    uint cb = (uint)f2b(correct), lb = (uint)f2b(latent);
                    if (i == 0)      { pc0 = cb;        pl0 = lb; }
                    else if (i == 1) { pc0 |= cb << 16; pl0 |= lb << 16; }
                    else if (i == 2) { pc1 = cb;        pl1 = lb; }
                    else             { pc1 |= cb << 16; pl1 |= lb << 16; }
                }
                float nxt = fmaf(kt, oml, l);
                latent = fminf(fmaxf(nxt, 1e-6f), 1.f - 1e-6f);
            }
            if (fb) {
                stg[0][tid * 21 + j4 * 2]     = pc0;
                stg[0][tid * 21 + j4 * 2 + 1] = pc1;
                stg[1][tid * 21 + j4 * 2]     = pl0;
                stg[1][tid * 21 + j4 * 2 + 1] = pl1;
            }
        }
        __syncthreads();
        // ---- cooperative stores
        if (!fb) {
            #pragma unroll
            for (int k2 = 0; k2 < 20; k2++) {
                int gix = tid + k2 * 64;                // 0..1279
                int r = gix / 20, q = gix - r * 20;     // 20 uint2 per row
                uint2 vc = *(const uint2*)&stg[0][r * 42 + q * 2];
                uint2 vl = *(const uint2*)&stg[1][r * 42 + q * 2];
                size_t off = (size_t)(b0 + r) * 800 + (size_t)c * 160 + q * 8;
                *(uint2*)(cgb + off) = vc;
                *(uint2*)(lgb + off) = vl;
            }
        } else {
            #pragma unroll
            for (int k2 = 0; k2 < 10; k2++) {
                int gix = tid + k2 * 64;                // 0..639
                int r = gix / 10, q = gix - r * 10;
                size_t off = (size_t)(b0 + r) * 400 + (size_t)c * 80 + q * 4;
                *(uint*)(cgb + off) = stg[0][r * 21 + q];
                *(uint*)(lgb + off) = stg[1][r * 21 + q];
            }
        }
        __syncthreads();   // stg reuse guard (lgkm only; stores stay in flight)
    }
}

// ---------------------------------------------------------------- launch
extern "C" void kernel_launch(void* const* d_in, const int* in_sizes, int n_in,
                              void* d_out, int out_size, void* d_ws, size_t ws_size,
                              hipStream_t stream) {
    const int* X = (const int*)d_in[0];
    const int* y = (const int*)d_in[1];

    char* ws = (char*)d_ws;
    ushort_t* conv  = (ushort_t*)(ws);                 // 1,031,178 B used
    ushort_t* WT1   = (ushort_t*)(ws + 1048576);       // 512 KB
    ushort_t* WT2   = (ushort_t*)(ws + 1572864);       // 512 KB
    ushort_t* h1    = (ushort_t*)(ws + 2097152);       // 1 MB (1024x512 bf16)
    ushort_t* h2    = (ushort_t*)(ws + 3145728);       // 1 MB
    float*    table = (float*)(ws + 4194304);          // 32 KB

    prep_kernel<<<dim3(2527, 1, 1), 256, 0, stream>>>(
        d_in[2], d_in[3], d_in[4], d_in[5], d_in[6], d_in[7], d_in[8],
        conv, WT1, WT2);
    mlp_layer<<<dim3(16, 8, 1), 256, 0, stream>>>(conv + OFF_EMB, WT1, conv + OFF_B1, h1, SS - 1);
    mlp_layer<<<dim3(16, 8, 1), 256, 0, stream>>>(h1, WT2, conv + OFF_B2, h2, 1023);
    params_kernel<<<dim3(1250, 1, 1), 256, 0, stream>>>(h2, conv, table);
    scan_kernel<<<dim3(BB_ / 64, 1, 1), 64, 0, stream>>>(
        X, y, table, (const uint*)d_in[2], (void*)d_out);
}